// Round 1
// baseline (75.755 us; speedup 1.0000x reference)
//
#include <hip/hip_runtime.h>
#include <hip/hip_bf16.h>
#include <stdint.h>

// RefBasedDeepMetric: out[b] = ||x_b@W + b||^2 + mean_r||refs_r@W + b||^2 - 2*(x_b@W + b). t
// where t = (mean_r refs_r)@W + b.  Both big terms are row-norm-reduced 4096x1024x1024
// GEMMs -> fused bf16 MFMA kernel, no M x N output materialization.

typedef __attribute__((ext_vector_type(8))) short short8;
typedef __attribute__((ext_vector_type(4))) float f32x4;

__device__ __forceinline__ short f2bf(float f) {
  uint32_t u = __builtin_bit_cast(uint32_t, f);
  uint32_t r = (u + 0x7fffu + ((u >> 16) & 1u)) >> 16;  // RNE
  return (short)r;
}
__device__ __forceinline__ float bf2f(short s) {
  uint32_t u = ((uint32_t)(uint16_t)s) << 16;
  return __builtin_bit_cast(float, u);
}

// ---- workspace layout (bytes) ----
#define WS_XB 0u          // x bf16        4096*1024*2 = 8388608
#define WS_RB 8388608u    // refs bf16     8388608
#define WS_WT 16777216u   // W^T bf16      1024*1024*2 = 2097152
#define WS_CS 18874368u   // colsum f32    4096
#define WS_TV 18878464u   // t vector f32  4096
#define WS_XP 18882560u   // xpart f32     16384
#define WS_RR 18898944u   // refrow f32    16384
#define WS_SC 18915328u   // scalar        16

// ---- convert f32 -> bf16 (vectorized float4 -> 4x bf16) ----
__global__ void k_convert(const float* __restrict__ in, short* __restrict__ out, int n4) {
  int i = blockIdx.x * blockDim.x + threadIdx.x;
  int stride = gridDim.x * blockDim.x;
  for (; i < n4; i += stride) {
    float4 v = ((const float4*)in)[i];
    short o0 = f2bf(v.x), o1 = f2bf(v.y), o2 = f2bf(v.z), o3 = f2bf(v.w);
    uint32_t lo = (uint16_t)o0 | ((uint32_t)(uint16_t)o1 << 16);
    uint32_t hi = (uint16_t)o2 | ((uint32_t)(uint16_t)o3 << 16);
    ((uint2*)out)[i] = make_uint2(lo, hi);
  }
}

// ---- convert refs -> bf16 and accumulate column sums ----
__global__ void k_convert_refs(const float* __restrict__ in, short* __restrict__ out,
                               float* __restrict__ colsum) {
  int t = threadIdx.x;
  int c0 = t * 4;
  int r0 = blockIdx.x * 32;
  float s0 = 0.f, s1 = 0.f, s2 = 0.f, s3 = 0.f;
  for (int r = r0; r < r0 + 32; ++r) {
    float4 v = *(const float4*)&in[(size_t)r * 1024 + c0];
    s0 += v.x; s1 += v.y; s2 += v.z; s3 += v.w;
    uint32_t lo = (uint16_t)f2bf(v.x) | ((uint32_t)(uint16_t)f2bf(v.y) << 16);
    uint32_t hi = (uint16_t)f2bf(v.z) | ((uint32_t)(uint16_t)f2bf(v.w) << 16);
    *(uint2*)&out[(size_t)r * 1024 + c0] = make_uint2(lo, hi);
  }
  atomicAdd(&colsum[c0 + 0], s0);
  atomicAdd(&colsum[c0 + 1], s1);
  atomicAdd(&colsum[c0 + 2], s2);
  atomicAdd(&colsum[c0 + 3], s3);
}

// ---- transpose-convert W (1024x1024 f32, [k][n]) -> Wt bf16 [n][k] ----
__global__ void k_transpose_w(const float* __restrict__ W, short* __restrict__ Wt) {
  __shared__ short tile[64][68];  // +4 pad breaks bank conflicts
  int t = threadIdx.x;
  int tk = (blockIdx.x >> 4) * 64, tn = (blockIdx.x & 15) * 64;
  int kk = t >> 4;           // 0..15
  int nn4 = (t & 15) * 4;
#pragma unroll
  for (int p = 0; p < 4; ++p) {
    int k = kk + p * 16;
    float4 v = *(const float4*)&W[(size_t)(tk + k) * 1024 + tn + nn4];
    tile[nn4 + 0][k] = f2bf(v.x);
    tile[nn4 + 1][k] = f2bf(v.y);
    tile[nn4 + 2][k] = f2bf(v.z);
    tile[nn4 + 3][k] = f2bf(v.w);
  }
  __syncthreads();
  int nn = t >> 4;
  int kk4 = (t & 15) * 4;
#pragma unroll
  for (int p = 0; p < 4; ++p) {
    int n = nn + p * 16;
    uint32_t lo = (uint16_t)tile[n][kk4 + 0] | ((uint32_t)(uint16_t)tile[n][kk4 + 1] << 16);
    uint32_t hi = (uint16_t)tile[n][kk4 + 2] | ((uint32_t)(uint16_t)tile[n][kk4 + 3] << 16);
    *(uint2*)&Wt[(size_t)(tn + n) * 1024 + tk + kk4] = make_uint2(lo, hi);
  }
}

// ---- t[n] = (colsum/R) @ W[:,n] + b[n], via Wt rows; one wave per n ----
__global__ void k_tvec(const short* __restrict__ Wt, const float* __restrict__ colsum,
                       const float* __restrict__ bias, float* __restrict__ tv) {
  int w = threadIdx.x >> 6, l = threadIdx.x & 63;
  int n = blockIdx.x * 4 + w;
  float s = 0.f;
  for (int k = l; k < 1024; k += 64)
    s += colsum[k] * (1.0f / 4096.0f) * bf2f(Wt[(size_t)n * 1024 + k]);
#pragma unroll
  for (int off = 32; off; off >>= 1) s += __shfl_down(s, off, 64);
  if (l == 0) tv[n] = s + bias[n];
}

// ---- main fused GEMM: per-row sum((v)^2) and sum(v*t), v = row@W + b ----
// 128x128 tile, BK=64, 4 waves (2x2), 16x16x32 bf16 MFMA.
// LDS staged via global_load_lds width=16, XOR-swizzled via pre-swizzled global src.
__global__ __launch_bounds__(256) void k_main(
    const short* __restrict__ Xb, const short* __restrict__ Rb,
    const short* __restrict__ Wt, const float* __restrict__ bias,
    const float* __restrict__ tv, float* __restrict__ xpart,
    float* __restrict__ refrow) {
  __shared__ __align__(16) short As[128 * 64];
  __shared__ __align__(16) short Bs[128 * 64];
  const int t = threadIdx.x;
  const int w = t >> 6, l = t & 63;
  const int wr = w >> 1, wc = w & 1;
  const int bx = blockIdx.x;
  const int nt = bx & 7;        // N tile 0..7
  const int mt = bx >> 3;       // 0..63 ; <32 -> x rows, >=32 -> refs rows
  const bool is_x = (mt < 32);
  const short* Am = is_x ? Xb : Rb;
  const int m0 = (is_x ? mt : (mt - 32)) * 128;
  const int n0 = nt * 128;

  const int srow = t >> 3;   // 0..31
  const int sslot = t & 7;   // 16B slot within 128B row

  f32x4 acc[4][4] = {};

  for (int kt = 0; kt < 16; ++kt) {
    const int k0 = kt * 64;
    __syncthreads();  // previous tile fully consumed
#pragma unroll
    for (int issue = 0; issue < 4; ++issue) {
      const int row = srow + issue * 32;
      const int sg = sslot ^ (row & 7);  // pre-swizzled global source (rule #21)
      const short* ga = Am + ((size_t)(m0 + row) * 1024 + k0 + sg * 8);
      const short* gb = Wt + ((size_t)(n0 + row) * 1024 + k0 + sg * 8);
      char* la = (char*)As + issue * 4096 + w * 1024;  // wave-uniform base + lane*16
      char* lb = (char*)Bs + issue * 4096 + w * 1024;
      __builtin_amdgcn_global_load_lds(
          (const __attribute__((address_space(1))) unsigned int*)ga,
          (__attribute__((address_space(3))) unsigned int*)la, 16, 0, 0);
      __builtin_amdgcn_global_load_lds(
          (const __attribute__((address_space(1))) unsigned int*)gb,
          (__attribute__((address_space(3))) unsigned int*)lb, 16, 0, 0);
    }
    __syncthreads();  // drains vmcnt(0): staged data visible
#pragma unroll
    for (int kk = 0; kk < 2; ++kk) {
      short8 af[4], bfr[4];
#pragma unroll
      for (int i = 0; i < 4; ++i) {
        const int ra = wr * 64 + i * 16 + (l & 15);
        const int rb = wc * 64 + i * 16 + (l & 15);
        const int s = (l >> 4) + kk * 4;
        af[i]  = *(const short8*)&As[ra * 64 + ((s ^ (ra & 7)) * 8)];
        bfr[i] = *(const short8*)&Bs[rb * 64 + ((s ^ (rb & 7)) * 8)];
      }
#pragma unroll
      for (int i = 0; i < 4; ++i)
#pragma unroll
        for (int j2 = 0; j2 < 4; ++j2)
          acc[i][j2] = __builtin_amdgcn_mfma_f32_16x16x32_bf16(af[i], bfr[j2], acc[i][j2], 0, 0, 0);
    }
  }

  // epilogue: v = acc + bias[col]; per-row sums of v^2 and v*t[col]
  float bv[4], tvv[4];
#pragma unroll
  for (int n4 = 0; n4 < 4; ++n4) {
    const int col = n0 + wc * 64 + n4 * 16 + (l & 15);
    bv[n4] = bias[col];
    tvv[n4] = tv[col];
  }
#pragma unroll
  for (int m4 = 0; m4 < 4; ++m4) {
#pragma unroll
    for (int j = 0; j < 4; ++j) {
      float sq = 0.f, cr = 0.f;
#pragma unroll
      for (int n4 = 0; n4 < 4; ++n4) {
        const float v = acc[m4][n4][j] + bv[n4];
        sq += v * v;
        cr += v * tvv[n4];
      }
      // reduce over the 16 lanes sharing this row (lane bits 0..3 vary the column)
#pragma unroll
      for (int off = 1; off < 16; off <<= 1) {
        sq += __shfl_xor(sq, off, 64);
        cr += __shfl_xor(cr, off, 64);
      }
      if ((l & 15) == 0) {
        const int rm = m0 + wr * 64 + m4 * 16 + (l >> 4) * 4 + j;
        if (is_x) atomicAdd(&xpart[rm], sq - 2.0f * cr);
        else      atomicAdd(&refrow[rm], sq);
      }
    }
  }
}

// ---- reduce refrow -> mean_sq_ref scalar ----
__global__ void k_reduce(const float* __restrict__ refrow, float* __restrict__ scalar) {
  float s = 0.f;
  for (int i = threadIdx.x; i < 4096; i += 256) s += refrow[i];
#pragma unroll
  for (int off = 32; off; off >>= 1) s += __shfl_down(s, off, 64);
  __shared__ float sh[4];
  int w = threadIdx.x >> 6, l = threadIdx.x & 63;
  if (l == 0) sh[w] = s;
  __syncthreads();
  if (threadIdx.x == 0) scalar[0] = (sh[0] + sh[1] + sh[2] + sh[3]) * (1.0f / 4096.0f);
}

// ---- final: out[b] = xpart[b] + mean_sq_ref ----
__global__ void k_final(const float* __restrict__ xpart, const float* __restrict__ scalar,
                        float* __restrict__ out) {
  int i = blockIdx.x * 256 + threadIdx.x;
  out[i] = xpart[i] + scalar[0];
}

extern "C" void kernel_launch(void* const* d_in, const int* in_sizes, int n_in,
                              void* d_out, int out_size, void* d_ws, size_t ws_size,
                              hipStream_t stream) {
  const float* x    = (const float*)d_in[0];
  const float* refs = (const float*)d_in[1];
  const float* W    = (const float*)d_in[2];
  const float* bias = (const float*)d_in[3];
  float* out = (float*)d_out;
  char* ws = (char*)d_ws;

  short* xb     = (short*)(ws + WS_XB);
  short* rb     = (short*)(ws + WS_RB);
  short* wt     = (short*)(ws + WS_WT);
  float* colsum = (float*)(ws + WS_CS);
  float* tvv    = (float*)(ws + WS_TV);
  float* xpart  = (float*)(ws + WS_XP);
  float* refrow = (float*)(ws + WS_RR);
  float* scalar = (float*)(ws + WS_SC);

  // zero all accumulator regions (colsum .. scalar) — harness does not re-poison
  hipMemsetAsync(ws + WS_CS, 0, (WS_SC + 16) - WS_CS, stream);

  hipLaunchKernelGGL(k_convert, dim3(1024), dim3(256), 0, stream, x, xb, 4096 * 1024 / 4);
  hipLaunchKernelGGL(k_convert_refs, dim3(128), dim3(256), 0, stream, refs, rb, colsum);
  hipLaunchKernelGGL(k_transpose_w, dim3(256), dim3(256), 0, stream, W, wt);
  hipLaunchKernelGGL(k_tvec, dim3(256), dim3(256), 0, stream, wt, colsum, bias, tvv);
  hipLaunchKernelGGL(k_main, dim3(512), dim3(256), 0, stream, xb, rb, wt, bias, tvv, xpart, refrow);
  hipLaunchKernelGGL(k_reduce, dim3(1), dim3(256), 0, stream, refrow, scalar);
  hipLaunchKernelGGL(k_final, dim3(16), dim3(256), 0, stream, xpart, scalar, out);
}

// Round 3
// 59.827 us; speedup vs baseline: 1.2662x; 1.2662x over previous
//
#include <hip/hip_runtime.h>
#include <hip/hip_bf16.h>
#include <stdint.h>

// RefBasedDeepMetric: out[b] = ||x_b@W + b||^2 + mean_r||refs_r@W + b||^2 - 2*(x_b@W + b).t
// where t = (mean_r refs_r)@W + b.  Both big terms are row-norm-reduced 4096x1024x1024
// GEMMs -> fused bf16 MFMA kernel, no MxN output materialization.
// R1: removed hipMemsetAsync (was 40us slow byte-fill); atomic-free colsum; fused prep.
// R2: fix zeroing — refrow was never cleared (accumulated across graph replays).

typedef __attribute__((ext_vector_type(8))) short short8;
typedef __attribute__((ext_vector_type(4))) float f32x4;

__device__ __forceinline__ short f2bf(float f) {
  uint32_t u = __builtin_bit_cast(uint32_t, f);
  uint32_t r = (u + 0x7fffu + ((u >> 16) & 1u)) >> 16;  // RNE
  return (short)r;
}
__device__ __forceinline__ float bf2f(short s) {
  uint32_t u = ((uint32_t)(uint16_t)s) << 16;
  return __builtin_bit_cast(float, u);
}

// ---- workspace layout (bytes) ----
#define WS_XB 0u           // x bf16            4096*1024*2 = 8388608
#define WS_RB 8388608u     // refs bf16         8388608
#define WS_WT 16777216u    // W^T bf16          2097152
#define WS_CP 18874368u    // colsum partials   128*1024*4 = 524288
#define WS_CS 19398656u    // colsum f32        4096
#define WS_TV 19402752u    // t vector f32      4096
#define WS_XP 19406848u    // xpart f32         16384
#define WS_RR 19423232u    // refrow f32        16384

// ---- fused prep: convert x, convert refs (+colsum partials), transpose W, zero accs ----
// blocks [0,512): x f32->bf16            blocks [512,640): refs f32->bf16 + colsum partials
// blocks [640,896): W transpose->bf16    blocks [896,900): zero xpart+refrow (8192 floats)
__global__ __launch_bounds__(256) void k_prep(
    const float* __restrict__ x, const float* __restrict__ refs,
    const float* __restrict__ W, short* __restrict__ xb, short* __restrict__ rb,
    short* __restrict__ wt, float* __restrict__ cspart, float* __restrict__ zacc) {
  __shared__ short tile[64][68];
  const int b = blockIdx.x, t = threadIdx.x;
  if (b < 512) {
    // convert x: 1048576 float4s, grid-stride over 512*256 threads (8 iters)
    for (int i = b * 256 + t; i < 1048576; i += 512 * 256) {
      float4 v = ((const float4*)x)[i];
      uint32_t lo = (uint16_t)f2bf(v.x) | ((uint32_t)(uint16_t)f2bf(v.y) << 16);
      uint32_t hi = (uint16_t)f2bf(v.z) | ((uint32_t)(uint16_t)f2bf(v.w) << 16);
      ((uint2*)xb)[i] = make_uint2(lo, hi);
    }
  } else if (b < 640) {
    // refs: 32 rows per block, thread owns 4 columns; partial colsums, no atomics
    const int rblk = b - 512;
    const int c0 = t * 4;
    float s0 = 0.f, s1 = 0.f, s2 = 0.f, s3 = 0.f;
    for (int r = rblk * 32; r < rblk * 32 + 32; ++r) {
      float4 v = *(const float4*)&refs[(size_t)r * 1024 + c0];
      s0 += v.x; s1 += v.y; s2 += v.z; s3 += v.w;
      uint32_t lo = (uint16_t)f2bf(v.x) | ((uint32_t)(uint16_t)f2bf(v.y) << 16);
      uint32_t hi = (uint16_t)f2bf(v.z) | ((uint32_t)(uint16_t)f2bf(v.w) << 16);
      *(uint2*)&rb[(size_t)r * 1024 + c0] = make_uint2(lo, hi);
    }
    cspart[rblk * 1024 + c0 + 0] = s0;
    cspart[rblk * 1024 + c0 + 1] = s1;
    cspart[rblk * 1024 + c0 + 2] = s2;
    cspart[rblk * 1024 + c0 + 3] = s3;
  } else if (b < 896) {
    // transpose-convert W [k][n] f32 -> Wt [n][k] bf16, 64x64 tiles
    const int tb = b - 640;
    const int tk = (tb >> 4) * 64, tn = (tb & 15) * 64;
    const int kk = t >> 4, nn4 = (t & 15) * 4;
#pragma unroll
    for (int p = 0; p < 4; ++p) {
      int k = kk + p * 16;
      float4 v = *(const float4*)&W[(size_t)(tk + k) * 1024 + tn + nn4];
      tile[nn4 + 0][k] = f2bf(v.x);
      tile[nn4 + 1][k] = f2bf(v.y);
      tile[nn4 + 2][k] = f2bf(v.z);
      tile[nn4 + 3][k] = f2bf(v.w);
    }
    __syncthreads();
    const int nn = t >> 4, kk4 = (t & 15) * 4;
#pragma unroll
    for (int p = 0; p < 4; ++p) {
      int n = nn + p * 16;
      uint32_t lo = (uint16_t)tile[n][kk4 + 0] | ((uint32_t)(uint16_t)tile[n][kk4 + 1] << 16);
      uint32_t hi = (uint16_t)tile[n][kk4 + 2] | ((uint32_t)(uint16_t)tile[n][kk4 + 3] << 16);
      *(uint2*)&wt[(size_t)(tn + n) * 1024 + tk + kk4] = make_uint2(lo, hi);
    }
  } else {
    // zero xpart + refrow: 8192 floats = 2048 float4s; 1024 threads x 2 each
    const int i = (b - 896) * 256 + t;
    ((float4*)zacc)[i]        = make_float4(0.f, 0.f, 0.f, 0.f);
    ((float4*)zacc)[i + 1024] = make_float4(0.f, 0.f, 0.f, 0.f);
  }
}

// ---- colsum[k] = sum_p cspart[p][k] ----
__global__ void k_colsum(const float* __restrict__ cspart, float* __restrict__ colsum) {
  const int k = blockIdx.x * 256 + threadIdx.x;
  float s = 0.f;
  for (int p = 0; p < 128; ++p) s += cspart[p * 1024 + k];
  colsum[k] = s;
}

// ---- t[n] = (colsum/R) @ W[:,n] + b[n], via Wt rows; one wave per n ----
__global__ void k_tvec(const short* __restrict__ Wt, const float* __restrict__ colsum,
                       const float* __restrict__ bias, float* __restrict__ tv) {
  int w = threadIdx.x >> 6, l = threadIdx.x & 63;
  int n = blockIdx.x * 4 + w;
  float s = 0.f;
  for (int k = l; k < 1024; k += 64)
    s += colsum[k] * (1.0f / 4096.0f) * bf2f(Wt[(size_t)n * 1024 + k]);
#pragma unroll
  for (int off = 32; off; off >>= 1) s += __shfl_down(s, off, 64);
  if (l == 0) tv[n] = s + bias[n];
}

// ---- main fused GEMM: per-row sum(v^2) and sum(v*t), v = row@W + b ----
// 128x128 tile, BK=64, 4 waves (2x2), 16x16x32 bf16 MFMA.
// LDS via global_load_lds width=16; XOR-swizzle via pre-swizzled global src (rule #21).
__global__ __launch_bounds__(256) void k_main(
    const short* __restrict__ Xb, const short* __restrict__ Rb,
    const short* __restrict__ Wt, const float* __restrict__ bias,
    const float* __restrict__ tv, float* __restrict__ xpart,
    float* __restrict__ refrow) {
  __shared__ __align__(16) short As[128 * 64];
  __shared__ __align__(16) short Bs[128 * 64];
  const int t = threadIdx.x;
  const int w = t >> 6, l = t & 63;
  const int wr = w >> 1, wc = w & 1;
  const int bx = blockIdx.x;
  const int nt = bx & 7;        // N tile 0..7
  const int mt = bx >> 3;       // 0..63 ; <32 -> x rows, >=32 -> refs rows
  const bool is_x = (mt < 32);
  const short* Am = is_x ? Xb : Rb;
  const int m0 = (is_x ? mt : (mt - 32)) * 128;
  const int n0 = nt * 128;

  const int srow = t >> 3;   // 0..31
  const int sslot = t & 7;   // 16B slot within 128B row

  f32x4 acc[4][4] = {};

  for (int kt = 0; kt < 16; ++kt) {
    const int k0 = kt * 64;
    __syncthreads();  // previous tile fully consumed
#pragma unroll
    for (int issue = 0; issue < 4; ++issue) {
      const int row = srow + issue * 32;
      const int sg = sslot ^ (row & 7);  // pre-swizzled global source
      const short* ga = Am + ((size_t)(m0 + row) * 1024 + k0 + sg * 8);
      const short* gb = Wt + ((size_t)(n0 + row) * 1024 + k0 + sg * 8);
      char* la = (char*)As + issue * 4096 + w * 1024;  // wave-uniform base + lane*16
      char* lb = (char*)Bs + issue * 4096 + w * 1024;
      __builtin_amdgcn_global_load_lds(
          (const __attribute__((address_space(1))) unsigned int*)ga,
          (__attribute__((address_space(3))) unsigned int*)la, 16, 0, 0);
      __builtin_amdgcn_global_load_lds(
          (const __attribute__((address_space(1))) unsigned int*)gb,
          (__attribute__((address_space(3))) unsigned int*)lb, 16, 0, 0);
    }
    __syncthreads();  // drains vmcnt(0): staged data visible
#pragma unroll
    for (int kk = 0; kk < 2; ++kk) {
      short8 af[4], bfr[4];
#pragma unroll
      for (int i = 0; i < 4; ++i) {
        const int ra = wr * 64 + i * 16 + (l & 15);
        const int rbw = wc * 64 + i * 16 + (l & 15);
        const int s = (l >> 4) + kk * 4;
        af[i]  = *(const short8*)&As[ra * 64 + ((s ^ (ra & 7)) * 8)];
        bfr[i] = *(const short8*)&Bs[rbw * 64 + ((s ^ (rbw & 7)) * 8)];
      }
#pragma unroll
      for (int i = 0; i < 4; ++i)
#pragma unroll
        for (int j2 = 0; j2 < 4; ++j2)
          acc[i][j2] = __builtin_amdgcn_mfma_f32_16x16x32_bf16(af[i], bfr[j2], acc[i][j2], 0, 0, 0);
    }
  }

  // epilogue: v = acc + bias[col]; per-row sums of v^2 and v*t[col]
  float bv[4], tvv[4];
#pragma unroll
  for (int n4 = 0; n4 < 4; ++n4) {
    const int col = n0 + wc * 64 + n4 * 16 + (l & 15);
    bv[n4] = bias[col];
    tvv[n4] = tv[col];
  }
#pragma unroll
  for (int m4 = 0; m4 < 4; ++m4) {
#pragma unroll
    for (int j = 0; j < 4; ++j) {
      float sq = 0.f, cr = 0.f;
#pragma unroll
      for (int n4 = 0; n4 < 4; ++n4) {
        const float v = acc[m4][n4][j] + bv[n4];
        sq += v * v;
        cr += v * tvv[n4];
      }
#pragma unroll
      for (int off = 1; off < 16; off <<= 1) {
        sq += __shfl_xor(sq, off, 64);
        cr += __shfl_xor(cr, off, 64);
      }
      if ((l & 15) == 0) {
        const int rm = m0 + wr * 64 + m4 * 16 + (l >> 4) * 4 + j;
        if (is_x) atomicAdd(&xpart[rm], sq - 2.0f * cr);
        else      atomicAdd(&refrow[rm], sq);
      }
    }
  }
}

// ---- tail: scalar = mean(refrow); out[b] = xpart[b] + scalar ----
__global__ void k_tail(const float* __restrict__ refrow, const float* __restrict__ xpart,
                       float* __restrict__ out) {
  __shared__ float sh[16];
  const int t = threadIdx.x;  // 1024 threads = 16 waves
  float s = 0.f;
  for (int i = t; i < 4096; i += 1024) s += refrow[i];
#pragma unroll
  for (int off = 32; off; off >>= 1) s += __shfl_down(s, off, 64);
  const int w = t >> 6, l = t & 63;
  if (l == 0) sh[w] = s;
  __syncthreads();
  if (t == 0) {
    float tot = 0.f;
#pragma unroll
    for (int i = 0; i < 16; ++i) tot += sh[i];
    sh[0] = tot * (1.0f / 4096.0f);
  }
  __syncthreads();
  const float ms = sh[0];
  for (int i = t; i < 4096; i += 1024) out[i] = xpart[i] + ms;
}

extern "C" void kernel_launch(void* const* d_in, const int* in_sizes, int n_in,
                              void* d_out, int out_size, void* d_ws, size_t ws_size,
                              hipStream_t stream) {
  const float* x    = (const float*)d_in[0];
  const float* refs = (const float*)d_in[1];
  const float* W    = (const float*)d_in[2];
  const float* bias = (const float*)d_in[3];
  float* out = (float*)d_out;
  char* ws = (char*)d_ws;

  short* xb     = (short*)(ws + WS_XB);
  short* rb     = (short*)(ws + WS_RB);
  short* wt     = (short*)(ws + WS_WT);
  float* cspart = (float*)(ws + WS_CP);
  float* colsum = (float*)(ws + WS_CS);
  float* tvv    = (float*)(ws + WS_TV);
  float* xpart  = (float*)(ws + WS_XP);
  float* refrow = (float*)(ws + WS_RR);

  hipLaunchKernelGGL(k_prep, dim3(900), dim3(256), 0, stream, x, refs, W, xb, rb, wt, cspart, xpart);
  hipLaunchKernelGGL(k_colsum, dim3(4), dim3(256), 0, stream, cspart, colsum);
  hipLaunchKernelGGL(k_tvec, dim3(256), dim3(256), 0, stream, wt, colsum, bias, tvv);
  hipLaunchKernelGGL(k_main, dim3(512), dim3(256), 0, stream, xb, rb, wt, bias, tvv, xpart, refrow);
  hipLaunchKernelGGL(k_tail, dim3(1), dim3(1024), 0, stream, refrow, xpart, out);
}

// Round 4
// 55.258 us; speedup vs baseline: 1.3709x; 1.0827x over previous
//
#include <hip/hip_runtime.h>
#include <hip/hip_bf16.h>
#include <stdint.h>

// RefBasedDeepMetric: out[b] = ||x_b@W + b||^2 + mean_r||refs_r@W + b||^2 - 2*(x_b@W + b).t
// where t = (mean_r refs_r)@W + b.  Both big terms are row-norm-reduced 4096x1024x1024
// GEMMs -> fused bf16 MFMA kernel, no MxN output materialization.
// R1: removed hipMemsetAsync (was 40us slow byte-fill); atomic-free colsum; fused prep.
// R2: fix zeroing — refrow was never cleared (accumulated across graph replays).
// R3: k_main double-buffered prefetch (T3 minimum 2-phase); prep rebalance (refs 512 blocks).

typedef __attribute__((ext_vector_type(8))) short short8;
typedef __attribute__((ext_vector_type(4))) float f32x4;

__device__ __forceinline__ short f2bf(float f) {
  uint32_t u = __builtin_bit_cast(uint32_t, f);
  uint32_t r = (u + 0x7fffu + ((u >> 16) & 1u)) >> 16;  // RNE
  return (short)r;
}
__device__ __forceinline__ float bf2f(short s) {
  uint32_t u = ((uint32_t)(uint16_t)s) << 16;
  return __builtin_bit_cast(float, u);
}

// ---- workspace layout (bytes) ----
#define WS_XB 0u           // x bf16            4096*1024*2 = 8388608
#define WS_RB 8388608u     // refs bf16         8388608
#define WS_WT 16777216u    // W^T bf16          2097152
#define WS_CP 18874368u    // colsum partials   512*1024*4 = 2097152
#define WS_CS 20971520u    // colsum f32        4096
#define WS_TV 20975616u    // t vector f32      4096
#define WS_XP 20979712u    // xpart f32         16384
#define WS_RR 20996096u    // refrow f32        16384

// ---- fused prep: convert x, convert refs (+colsum partials), transpose W, zero accs ----
// blocks [0,512): x f32->bf16             blocks [512,1024): refs f32->bf16 + colsum partials
// blocks [1024,1280): W transpose->bf16   blocks [1280,1284): zero xpart+refrow
__global__ __launch_bounds__(256) void k_prep(
    const float* __restrict__ x, const float* __restrict__ refs,
    const float* __restrict__ W, short* __restrict__ xb, short* __restrict__ rb,
    short* __restrict__ wt, float* __restrict__ cspart, float* __restrict__ zacc) {
  __shared__ short tile[64][68];
  const int b = blockIdx.x, t = threadIdx.x;
  if (b < 512) {
    // convert x: 1048576 float4s, grid-stride over 512*256 threads (8 iters)
    for (int i = b * 256 + t; i < 1048576; i += 512 * 256) {
      float4 v = ((const float4*)x)[i];
      uint32_t lo = (uint16_t)f2bf(v.x) | ((uint32_t)(uint16_t)f2bf(v.y) << 16);
      uint32_t hi = (uint16_t)f2bf(v.z) | ((uint32_t)(uint16_t)f2bf(v.w) << 16);
      ((uint2*)xb)[i] = make_uint2(lo, hi);
    }
  } else if (b < 1024) {
    // refs: 8 rows per block, thread owns 4 columns; partial colsums, no atomics
    const int rblk = b - 512;
    const int c0 = t * 4;
    float s0 = 0.f, s1 = 0.f, s2 = 0.f, s3 = 0.f;
    for (int r = rblk * 8; r < rblk * 8 + 8; ++r) {
      float4 v = *(const float4*)&refs[(size_t)r * 1024 + c0];
      s0 += v.x; s1 += v.y; s2 += v.z; s3 += v.w;
      uint32_t lo = (uint16_t)f2bf(v.x) | ((uint32_t)(uint16_t)f2bf(v.y) << 16);
      uint32_t hi = (uint16_t)f2bf(v.z) | ((uint32_t)(uint16_t)f2bf(v.w) << 16);
      *(uint2*)&rb[(size_t)r * 1024 + c0] = make_uint2(lo, hi);
    }
    cspart[rblk * 1024 + c0 + 0] = s0;
    cspart[rblk * 1024 + c0 + 1] = s1;
    cspart[rblk * 1024 + c0 + 2] = s2;
    cspart[rblk * 1024 + c0 + 3] = s3;
  } else if (b < 1280) {
    // transpose-convert W [k][n] f32 -> Wt [n][k] bf16, 64x64 tiles
    const int tb = b - 1024;
    const int tk = (tb >> 4) * 64, tn = (tb & 15) * 64;
    const int kk = t >> 4, nn4 = (t & 15) * 4;
#pragma unroll
    for (int p = 0; p < 4; ++p) {
      int k = kk + p * 16;
      float4 v = *(const float4*)&W[(size_t)(tk + k) * 1024 + tn + nn4];
      tile[nn4 + 0][k] = f2bf(v.x);
      tile[nn4 + 1][k] = f2bf(v.y);
      tile[nn4 + 2][k] = f2bf(v.z);
      tile[nn4 + 3][k] = f2bf(v.w);
    }
    __syncthreads();
    const int nn = t >> 4, kk4 = (t & 15) * 4;
#pragma unroll
    for (int p = 0; p < 4; ++p) {
      int n = nn + p * 16;
      uint32_t lo = (uint16_t)tile[n][kk4 + 0] | ((uint32_t)(uint16_t)tile[n][kk4 + 1] << 16);
      uint32_t hi = (uint16_t)tile[n][kk4 + 2] | ((uint32_t)(uint16_t)tile[n][kk4 + 3] << 16);
      *(uint2*)&wt[(size_t)(tn + n) * 1024 + tk + kk4] = make_uint2(lo, hi);
    }
  } else {
    // zero xpart + refrow: 8192 floats = 2048 float4s; 1024 threads x 2 each
    const int i = (b - 1280) * 256 + t;
    ((float4*)zacc)[i]        = make_float4(0.f, 0.f, 0.f, 0.f);
    ((float4*)zacc)[i + 1024] = make_float4(0.f, 0.f, 0.f, 0.f);
  }
}

// ---- colsum[k] = sum_p cspart[p][k]; 32 blocks x 32 cols, 8 partial-groups/LDS-reduce ----
__global__ void k_colsum(const float* __restrict__ cspart, float* __restrict__ colsum) {
  __shared__ float sh[8][32];
  const int t = threadIdx.x;
  const int c = t & 31, pg = t >> 5;       // 8 partial groups x 32 columns
  const int k = blockIdx.x * 32 + c;
  float s = 0.f;
  for (int i = 0; i < 64; ++i) s += cspart[(size_t)(pg * 64 + i) * 1024 + k];
  sh[pg][c] = s;
  __syncthreads();
  if (t < 32) {
    float tot = 0.f;
#pragma unroll
    for (int g = 0; g < 8; ++g) tot += sh[g][t];
    colsum[blockIdx.x * 32 + t] = tot;
  }
}

// ---- t[n] = (colsum/R) @ W[:,n] + b[n], via Wt rows; one wave per n ----
__global__ void k_tvec(const short* __restrict__ Wt, const float* __restrict__ colsum,
                       const float* __restrict__ bias, float* __restrict__ tv) {
  int w = threadIdx.x >> 6, l = threadIdx.x & 63;
  int n = blockIdx.x * 4 + w;
  float s = 0.f;
  for (int k = l; k < 1024; k += 64)
    s += colsum[k] * (1.0f / 4096.0f) * bf2f(Wt[(size_t)n * 1024 + k]);
#pragma unroll
  for (int off = 32; off; off >>= 1) s += __shfl_down(s, off, 64);
  if (l == 0) tv[n] = s + bias[n];
}

// ---- main fused GEMM: per-row sum(v^2) and sum(v*t), v = row@W + b ----
// 128x128 tile, BK=64, 4 waves (2x2), 16x16x32 bf16 MFMA.
// Double-buffered LDS, prefetch next K-tile before computing current (T3 2-phase).
// LDS via global_load_lds width=16; XOR-swizzle via pre-swizzled global src (rule #21).
__global__ __launch_bounds__(256) void k_main(
    const short* __restrict__ Xb, const short* __restrict__ Rb,
    const short* __restrict__ Wt, const float* __restrict__ bias,
    const float* __restrict__ tv, float* __restrict__ xpart,
    float* __restrict__ refrow) {
  __shared__ __align__(16) short As[2][128 * 64];
  __shared__ __align__(16) short Bs[2][128 * 64];
  const int t = threadIdx.x;
  const int w = t >> 6, l = t & 63;
  const int wr = w >> 1, wc = w & 1;
  const int bx = blockIdx.x;
  const int nt = bx & 7;        // N tile 0..7 (round-robin puts one nt per XCD: Wt panel L2-resident)
  const int mt = bx >> 3;       // 0..63 ; <32 -> x rows, >=32 -> refs rows
  const bool is_x = (mt < 32);
  const short* Am = is_x ? Xb : Rb;
  const int m0 = (is_x ? mt : (mt - 32)) * 128;
  const int n0 = nt * 128;

  const int srow = t >> 3;   // 0..31
  const int sslot = t & 7;   // 16B slot within 128B row

  f32x4 acc[4][4] = {};

  auto stage = [&](int buf, int kt) {
    const int k0 = kt * 64;
#pragma unroll
    for (int issue = 0; issue < 4; ++issue) {
      const int row = srow + issue * 32;
      const int sg = sslot ^ (row & 7);  // pre-swizzled global source
      const short* ga = Am + ((size_t)(m0 + row) * 1024 + k0 + sg * 8);
      const short* gb = Wt + ((size_t)(n0 + row) * 1024 + k0 + sg * 8);
      char* la = (char*)&As[buf][0] + issue * 4096 + w * 1024;  // + lane*16 implicit
      char* lb = (char*)&Bs[buf][0] + issue * 4096 + w * 1024;
      __builtin_amdgcn_global_load_lds(
          (const __attribute__((address_space(1))) unsigned int*)ga,
          (__attribute__((address_space(3))) unsigned int*)la, 16, 0, 0);
      __builtin_amdgcn_global_load_lds(
          (const __attribute__((address_space(1))) unsigned int*)gb,
          (__attribute__((address_space(3))) unsigned int*)lb, 16, 0, 0);
    }
  };

  // prologue: stage tile 0
  stage(0, 0);
  asm volatile("s_waitcnt vmcnt(0)" ::: "memory");
  __builtin_amdgcn_s_barrier();

  int cur = 0;
  for (int kt = 0; kt < 16; ++kt) {
    if (kt < 15) stage(cur ^ 1, kt + 1);   // issue next-tile loads; latency hides under MFMA
#pragma unroll
    for (int kk = 0; kk < 2; ++kk) {
      short8 af[4], bfr[4];
#pragma unroll
      for (int i = 0; i < 4; ++i) {
        const int ra = wr * 64 + i * 16 + (l & 15);
        const int rbw = wc * 64 + i * 16 + (l & 15);
        const int s = (l >> 4) + kk * 4;
        af[i]  = *(const short8*)&As[cur][ra * 64 + ((s ^ (ra & 7)) * 8)];
        bfr[i] = *(const short8*)&Bs[cur][rbw * 64 + ((s ^ (rbw & 7)) * 8)];
      }
#pragma unroll
      for (int i = 0; i < 4; ++i)
#pragma unroll
        for (int j2 = 0; j2 < 4; ++j2)
          acc[i][j2] = __builtin_amdgcn_mfma_f32_16x16x32_bf16(af[i], bfr[j2], acc[i][j2], 0, 0, 0);
    }
    asm volatile("s_waitcnt vmcnt(0)" ::: "memory");  // prefetch landed
    __builtin_amdgcn_s_barrier();
    cur ^= 1;
  }

  // epilogue: v = acc + bias[col]; per-row sums of v^2 and v*t[col]
  float bv[4], tvv[4];
#pragma unroll
  for (int n4 = 0; n4 < 4; ++n4) {
    const int col = n0 + wc * 64 + n4 * 16 + (l & 15);
    bv[n4] = bias[col];
    tvv[n4] = tv[col];
  }
#pragma unroll
  for (int m4 = 0; m4 < 4; ++m4) {
#pragma unroll
    for (int j = 0; j < 4; ++j) {
      float sq = 0.f, cr = 0.f;
#pragma unroll
      for (int n4 = 0; n4 < 4; ++n4) {
        const float v = acc[m4][n4][j] + bv[n4];
        sq += v * v;
        cr += v * tvv[n4];
      }
#pragma unroll
      for (int off = 1; off < 16; off <<= 1) {
        sq += __shfl_xor(sq, off, 64);
        cr += __shfl_xor(cr, off, 64);
      }
      if ((l & 15) == 0) {
        const int rm = m0 + wr * 64 + m4 * 16 + (l >> 4) * 4 + j;
        if (is_x) atomicAdd(&xpart[rm], sq - 2.0f * cr);
        else      atomicAdd(&refrow[rm], sq);
      }
    }
  }
}

// ---- tail: scalar = mean(refrow); out[b] = xpart[b] + scalar ----
__global__ void k_tail(const float* __restrict__ refrow, const float* __restrict__ xpart,
                       float* __restrict__ out) {
  __shared__ float sh[16];
  const int t = threadIdx.x;  // 1024 threads = 16 waves
  float s = 0.f;
  for (int i = t; i < 4096; i += 1024) s += refrow[i];
#pragma unroll
  for (int off = 32; off; off >>= 1) s += __shfl_down(s, off, 64);
  const int w = t >> 6, l = t & 63;
  if (l == 0) sh[w] = s;
  __syncthreads();
  if (t == 0) {
    float tot = 0.f;
#pragma unroll
    for (int i = 0; i < 16; ++i) tot += sh[i];
    sh[0] = tot * (1.0f / 4096.0f);
  }
  __syncthreads();
  const float ms = sh[0];
  for (int i = t; i < 4096; i += 1024) out[i] = xpart[i] + ms;
}

extern "C" void kernel_launch(void* const* d_in, const int* in_sizes, int n_in,
                              void* d_out, int out_size, void* d_ws, size_t ws_size,
                              hipStream_t stream) {
  const float* x    = (const float*)d_in[0];
  const float* refs = (const float*)d_in[1];
  const float* W    = (const float*)d_in[2];
  const float* bias = (const float*)d_in[3];
  float* out = (float*)d_out;
  char* ws = (char*)d_ws;

  short* xb     = (short*)(ws + WS_XB);
  short* rb     = (short*)(ws + WS_RB);
  short* wt     = (short*)(ws + WS_WT);
  float* cspart = (float*)(ws + WS_CP);
  float* colsum = (float*)(ws + WS_CS);
  float* tvv    = (float*)(ws + WS_TV);
  float* xpart  = (float*)(ws + WS_XP);
  float* refrow = (float*)(ws + WS_RR);

  hipLaunchKernelGGL(k_prep, dim3(1284), dim3(256), 0, stream, x, refs, W, xb, rb, wt, cspart, xpart);
  hipLaunchKernelGGL(k_colsum, dim3(32), dim3(256), 0, stream, cspart, colsum);
  hipLaunchKernelGGL(k_tvec, dim3(256), dim3(256), 0, stream, wt, colsum, bias, tvv);
  hipLaunchKernelGGL(k_main, dim3(512), dim3(256), 0, stream, xb, rb, wt, bias, tvv, xpart, refrow);
  hipLaunchKernelGGL(k_tail, dim3(1), dim3(1024), 0, stream, refrow, xpart, out);
}